// Round 3
// baseline (281.093 us; speedup 1.0000x reference)
//
#include <hip/hip_runtime.h>
#include <hip/hip_bf16.h>

#define N_NODES  10000
#define N_EDGES  320000
#define N_GRAPHS 64

__device__ __forceinline__ float sigm(float z) { return 1.0f / (1.0f + __expf(-z)); }

// ---------------- dtype detection ----------------
// flags[0]: edge_index is int32 (1) vs int64 (0)
// flags[1]: batch is int32 (1) vs int64 (0)
// flags[2]: floats are packed bf16 (1) vs f32 (0)
__global__ void detect_k(const unsigned int* __restrict__ ei_raw,
                         const unsigned int* __restrict__ batch_raw,
                         const unsigned int* __restrict__ x_raw,
                         int* __restrict__ flags) {
    __shared__ int s[3];
    if (threadIdx.x < 3) s[threadIdx.x] = 0;
    __syncthreads();
    int t = threadIdx.x;
    int nz = 0;
    for (int i = 2 * t + 1; i < 2000; i += 512) nz += (ei_raw[i] != 0);
    if (nz) atomicAdd(&s[0], nz);
    nz = 0;
    for (int i = 2 * t + 1; i < 2000; i += 512) nz += (batch_raw[i] != 0);
    if (nz) atomicAdd(&s[1], nz);
    int pl = 0;
    for (int i = t; i < 1000; i += 256) {
        unsigned e = (x_raw[i] >> 7) & 0xff;  // exponent of low-half-as-bf16
        pl += (e >= 100 && e <= 140);
    }
    if (pl) atomicAdd(&s[2], pl);
    __syncthreads();
    if (threadIdx.x == 0) {
        flags[0] = s[0] > 10 ? 1 : 0;
        flags[1] = s[1] > 10 ? 1 : 0;
        flags[2] = s[2] > 500 ? 1 : 0;
    }
}

// normalize ints to int32 arrays
__global__ void repack_int_k(const int* __restrict__ ei, const int* __restrict__ batch,
                             const int* __restrict__ flags, int* __restrict__ src,
                             int* __restrict__ dst, int* __restrict__ bat) {
    int i = blockIdx.x * blockDim.x + threadIdx.x;
    int i32e = flags[0], i32b = flags[1];
    if (i < N_EDGES) {
        src[i] = i32e ? ei[i] : ei[2 * i];
        dst[i] = i32e ? ei[N_EDGES + i] : ei[2 * (N_EDGES + i)];
    }
    if (i < N_NODES) bat[i] = i32b ? batch[i] : batch[2 * i];
}

// normalize floats to f32
__global__ void cvt_k(const void* __restrict__ in, float* __restrict__ out, int n,
                      const int* __restrict__ flags) {
    int i = blockIdx.x * blockDim.x + threadIdx.x;
    if (i >= n) return;
    if (flags[2]) {
        const unsigned short* p = (const unsigned short*)in;
        out[i] = __uint_as_float(((unsigned int)p[i]) << 16);
    } else {
        out[i] = ((const float*)in)[i];
    }
}

// ---------------- CSR build ----------------
__global__ void hist_k(const int* __restrict__ dst, int* __restrict__ deg, int E) {
    int e = blockIdx.x * blockDim.x + threadIdx.x;
    if (e < E) atomicAdd(&deg[dst[e]], 1);
}

__global__ void scan_k(const int* __restrict__ deg, int* __restrict__ offs,
                       int* __restrict__ cursor, int n) {
    __shared__ int buf[1024];
    __shared__ int carry;
    if (threadIdx.x == 0) carry = 0;
    __syncthreads();
    for (int base = 0; base < n; base += 1024) {
        int i = base + (int)threadIdx.x;
        int v = (i < n) ? deg[i] : 0;
        buf[threadIdx.x] = v;
        __syncthreads();
        for (int d = 1; d < 1024; d <<= 1) {
            int t = (threadIdx.x >= (unsigned)d) ? buf[threadIdx.x - d] : 0;
            __syncthreads();
            buf[threadIdx.x] += t;
            __syncthreads();
        }
        int incl = buf[threadIdx.x];
        int excl = incl - v + carry;
        if (i < n) { offs[i] = excl; cursor[i] = excl; }
        __syncthreads();
        if (threadIdx.x == 0) carry += buf[1023];
        __syncthreads();
    }
    if (threadIdx.x == 0) offs[n] = carry;
}

__global__ void scatter_k(const int* __restrict__ src, const int* __restrict__ dst,
                          int* __restrict__ cursor, int* __restrict__ csr, int E) {
    int e = blockIdx.x * blockDim.x + threadIdx.x;
    if (e < E) {
        int pos = atomicAdd(&cursor[dst[e]], 1);
        csr[pos] = src[e];
    }
}

// ---------------- EdgeConv1 node-level linear parts ----------------
// PQ1[n][c<128]  = x[n]·(W1[0:3]-W1[3:6])[c] + b1[c]   (P, dst part)
// PQ1[n][c>=128] = x[n]·W1[3:6][c-128]                 (Q, src part)
__global__ void pq1_k(const float* __restrict__ x, const float* __restrict__ W1,
                      const float* __restrict__ b1, float* __restrict__ PQ1, int n) {
    __shared__ float xs[96];
    int c = threadIdx.x;  // 0..255
    float k0, k1, k2, bias;
    if (c < 128) {
        k0 = W1[0 * 128 + c] - W1[3 * 128 + c];
        k1 = W1[1 * 128 + c] - W1[4 * 128 + c];
        k2 = W1[2 * 128 + c] - W1[5 * 128 + c];
        bias = b1[c];
    } else {
        int cc = c - 128;
        k0 = W1[3 * 128 + cc];
        k1 = W1[4 * 128 + cc];
        k2 = W1[5 * 128 + cc];
        bias = 0.f;
    }
    int n0 = blockIdx.x * 32;
    int nmax = min(32, n - n0);
    if (threadIdx.x < 96)
        xs[threadIdx.x] = (threadIdx.x < nmax * 3) ? x[n0 * 3 + threadIdx.x] : 0.f;
    __syncthreads();
    for (int t = 0; t < nmax; t++) {
        float v = bias + xs[t * 3 + 0] * k0 + xs[t * 3 + 1] * k1 + xs[t * 3 + 2] * k2;
        PQ1[(n0 + t) * 256 + c] = v;
    }
}

// one block (128 thr) per node: h1[i][c] = deg>0 ? sigmoid(P[i][c] + max_e Q[src_e][c]) : 0
__global__ void econv1_k(const float* __restrict__ PQ1, const int* __restrict__ offs,
                         const int* __restrict__ csr, float* __restrict__ h1) {
    int i = blockIdx.x;
    int c = threadIdx.x;  // 0..127
    int s = offs[i], e = offs[i + 1];
    float out = 0.f;
    if (e > s) {
        float zm = -3.4e38f;
        int k = s;
        for (; k + 3 < e; k += 4) {
            int j0 = csr[k], j1 = csr[k + 1], j2 = csr[k + 2], j3 = csr[k + 3];
            float q0 = PQ1[j0 * 256 + 128 + c];
            float q1 = PQ1[j1 * 256 + 128 + c];
            float q2 = PQ1[j2 * 256 + 128 + c];
            float q3 = PQ1[j3 * 256 + 128 + c];
            zm = fmaxf(zm, fmaxf(fmaxf(q0, q1), fmaxf(q2, q3)));
        }
        for (; k < e; k++) zm = fmaxf(zm, PQ1[csr[k] * 256 + 128 + c]);
        out = sigm(PQ1[i * 256 + c] + zm);
    }
    h1[i * 128 + c] = out;
}

// ---------------- EdgeConv2 weights: Wc[128][512] = [A2-B2 | B2] ----------------
__global__ void w2cat_k(const float* __restrict__ W2, const float* __restrict__ b2,
                        float* __restrict__ Wc, float* __restrict__ b2c) {
    int idx = blockIdx.x * blockDim.x + threadIdx.x;
    if (idx < 128 * 512) {
        int k = idx >> 9, j = idx & 511;
        float v;
        if (j < 256) v = W2[k * 256 + j] - W2[(128 + k) * 256 + j];
        else         v = W2[(128 + k) * 256 + (j - 256)];
        Wc[idx] = v;
    }
    if (idx < 256) b2c[idx] = b2[idx];
}

// ---------------- GEMM2: PQ2[10000,512] = h1[10000,128] @ Wc[128,512] (+b2 on P half) ----
__global__ __launch_bounds__(256) void gemm2_k(const float* __restrict__ h1,
                                               const float* __restrict__ Wc,
                                               const float* __restrict__ b2c,
                                               float* __restrict__ PQ2, int n) {
    __shared__ float As[32][132];
    __shared__ float Bs[128][64];
    int m0 = blockIdx.x * 32;
    int n0 = blockIdx.y * 64;
    int t = threadIdx.x;

    for (int it = 0; it < 4; it++) {
        int f4 = t + it * 256;
        int row = f4 >> 5, col = (f4 & 31) << 2;
        float4 v = make_float4(0.f, 0.f, 0.f, 0.f);
        if (m0 + row < n) v = *(const float4*)&h1[(m0 + row) * 128 + col];
        *(float4*)&As[row][col] = v;
    }
    for (int it = 0; it < 8; it++) {
        int f4 = t + it * 256;
        int row = f4 >> 4, col = (f4 & 15) << 2;
        *(float4*)&Bs[row][col] = *(const float4*)&Wc[row * 512 + n0 + col];
    }
    __syncthreads();

    int tr = t >> 4, tc = t & 15;
    float acc[2][4] = {};
#pragma unroll 4
    for (int k = 0; k < 128; k++) {
        float a0 = As[tr * 2 + 0][k];
        float a1 = As[tr * 2 + 1][k];
        float4 bb = *(float4*)&Bs[k][tc * 4];
        acc[0][0] += a0 * bb.x; acc[0][1] += a0 * bb.y; acc[0][2] += a0 * bb.z; acc[0][3] += a0 * bb.w;
        acc[1][0] += a1 * bb.x; acc[1][1] += a1 * bb.y; acc[1][2] += a1 * bb.z; acc[1][3] += a1 * bb.w;
    }

    int ncol = n0 + tc * 4;
    float bx = (ncol + 0 < 256) ? b2c[ncol + 0] : 0.f;
    float by = (ncol + 1 < 256) ? b2c[ncol + 1] : 0.f;
    float bz = (ncol + 2 < 256) ? b2c[ncol + 2] : 0.f;
    float bw = (ncol + 3 < 256) ? b2c[ncol + 3] : 0.f;
    for (int r = 0; r < 2; r++) {
        int m = m0 + tr * 2 + r;
        if (m < n) {
            float4 o = make_float4(acc[r][0] + bx, acc[r][1] + by, acc[r][2] + bz, acc[r][3] + bw);
            *(float4*)&PQ2[(size_t)m * 512 + ncol] = o;
        }
    }
}

// ---------------- EdgeConv2 + fused graph max-pool ----------------
__global__ void econv2_k(const float* __restrict__ PQ2, const int* __restrict__ offs,
                         const int* __restrict__ csr, const int* __restrict__ bat,
                         float* __restrict__ g) {
    int i = blockIdx.x;
    int s = offs[i], e = offs[i + 1];
    if (s == e) return;  // empty row -> h2 = 0, contributes nothing (g init 0)
    int c = threadIdx.x;  // 0..255
    float zm = -3.4e38f;
    int k = s;
    for (; k + 3 < e; k += 4) {
        int j0 = csr[k], j1 = csr[k + 1], j2 = csr[k + 2], j3 = csr[k + 3];
        float q0 = PQ2[(size_t)j0 * 512 + 256 + c];
        float q1 = PQ2[(size_t)j1 * 512 + 256 + c];
        float q2 = PQ2[(size_t)j2 * 512 + 256 + c];
        float q3 = PQ2[(size_t)j3 * 512 + 256 + c];
        zm = fmaxf(zm, fmaxf(fmaxf(q0, q1), fmaxf(q2, q3)));
    }
    for (; k < e; k++) zm = fmaxf(zm, PQ2[(size_t)csr[k] * 512 + 256 + c]);
    float h = sigm(PQ2[(size_t)i * 512 + c] + zm);  // > 0 always
    atomicMax((unsigned int*)&g[bat[i] * 256 + c], __float_as_uint(h));
}

// ---------------- head: out = sigmoid(g@W3+b3)@W4+b4, f32 out ----------------
__global__ void final_k(const float* __restrict__ g, const float* __restrict__ W3,
                        const float* __restrict__ b3, const float* __restrict__ W4,
                        const float* __restrict__ b4, float* __restrict__ out) {
    __shared__ float gs[256];
    __shared__ float ss[128];
    int b = blockIdx.x, t = threadIdx.x;  // 128 threads
    gs[t] = g[b * 256 + t];
    gs[t + 128] = g[b * 256 + 128 + t];
    __syncthreads();
    float acc = b3[t];
#pragma unroll 8
    for (int k = 0; k < 256; k++) acc += gs[k] * W3[k * 128 + t];
    ss[t] = sigm(acc);
    __syncthreads();
    if (t < 10) {
        float o = b4[t];
#pragma unroll 8
        for (int k = 0; k < 128; k++) o += ss[k] * W4[k * 10 + t];
        out[b * 10 + t] = o;  // reference output dtype is float32
    }
}

extern "C" void kernel_launch(void* const* d_in, const int* in_sizes, int n_in,
                              void* d_out, int out_size, void* d_ws, size_t ws_size,
                              hipStream_t stream) {
    const void* x_raw  = d_in[0];
    const void* ei_raw = d_in[1];
    const void* b_raw  = d_in[2];
    const void* W1_raw = d_in[3];
    const void* b1_raw = d_in[4];
    const void* W2_raw = d_in[5];
    const void* b2_raw = d_in[6];
    const void* W3_raw = d_in[7];
    const void* b3_raw = d_in[8];
    const void* W4_raw = d_in[9];
    const void* b4_raw = d_in[10];

    char* ws = (char*)d_ws;
    size_t off = 0;
    auto alloc = [&](size_t bytes) {
        void* p = ws + off;
        off += (bytes + 255) & ~(size_t)255;
        return p;
    };
    int*   flags  = (int*)alloc(16);
    int*   src    = (int*)alloc(N_EDGES * 4);
    int*   dst    = (int*)alloc(N_EDGES * 4);
    int*   bat    = (int*)alloc(N_NODES * 4);
    float* xf     = (float*)alloc(N_NODES * 3 * 4);
    float* W1f    = (float*)alloc(768 * 4);
    float* b1f    = (float*)alloc(128 * 4);
    float* W2f    = (float*)alloc(65536 * 4);
    float* b2f    = (float*)alloc(256 * 4);
    float* W3f    = (float*)alloc(32768 * 4);
    float* b3f    = (float*)alloc(128 * 4);
    float* W4f    = (float*)alloc(1280 * 4);
    float* b4f    = (float*)alloc(16 * 4);
    int*   deg    = (int*)alloc(N_NODES * 4);
    int*   offs   = (int*)alloc((N_NODES + 1) * 4);
    int*   cursor = (int*)alloc(N_NODES * 4);
    int*   csr    = (int*)alloc(N_EDGES * 4);
    float* PQ1    = (float*)alloc((size_t)N_NODES * 256 * 4);
    float* h1     = (float*)alloc((size_t)N_NODES * 128 * 4);
    float* Wc     = (float*)alloc(128 * 512 * 4);
    float* b2c    = (float*)alloc(256 * 4);
    float* PQ2    = (float*)alloc((size_t)N_NODES * 512 * 4);
    float* g      = (float*)alloc(N_GRAPHS * 256 * 4);

    hipMemsetAsync(deg, 0, N_NODES * 4, stream);
    hipMemsetAsync(g, 0, N_GRAPHS * 256 * 4, stream);

    detect_k<<<1, 256, 0, stream>>>((const unsigned int*)ei_raw, (const unsigned int*)b_raw,
                                    (const unsigned int*)x_raw, flags);
    repack_int_k<<<(N_EDGES + 255) / 256, 256, 0, stream>>>((const int*)ei_raw, (const int*)b_raw,
                                                            flags, src, dst, bat);
    cvt_k<<<(30000 + 255) / 256, 256, 0, stream>>>(x_raw, xf, 30000, flags);
    cvt_k<<<3, 256, 0, stream>>>(W1_raw, W1f, 768, flags);
    cvt_k<<<1, 256, 0, stream>>>(b1_raw, b1f, 128, flags);
    cvt_k<<<256, 256, 0, stream>>>(W2_raw, W2f, 65536, flags);
    cvt_k<<<1, 256, 0, stream>>>(b2_raw, b2f, 256, flags);
    cvt_k<<<128, 256, 0, stream>>>(W3_raw, W3f, 32768, flags);
    cvt_k<<<1, 256, 0, stream>>>(b3_raw, b3f, 128, flags);
    cvt_k<<<5, 256, 0, stream>>>(W4_raw, W4f, 1280, flags);
    cvt_k<<<1, 256, 0, stream>>>(b4_raw, b4f, 10, flags);

    hist_k<<<(N_EDGES + 255) / 256, 256, 0, stream>>>(dst, deg, N_EDGES);
    scan_k<<<1, 1024, 0, stream>>>(deg, offs, cursor, N_NODES);
    scatter_k<<<(N_EDGES + 255) / 256, 256, 0, stream>>>(src, dst, cursor, csr, N_EDGES);

    pq1_k<<<(N_NODES + 31) / 32, 256, 0, stream>>>(xf, W1f, b1f, PQ1, N_NODES);
    econv1_k<<<N_NODES, 128, 0, stream>>>(PQ1, offs, csr, h1);

    w2cat_k<<<(128 * 512) / 256, 256, 0, stream>>>(W2f, b2f, Wc, b2c);
    gemm2_k<<<dim3((N_NODES + 31) / 32, 8), 256, 0, stream>>>(h1, Wc, b2c, PQ2, N_NODES);

    econv2_k<<<N_NODES, 256, 0, stream>>>(PQ2, offs, csr, bat, g);
    final_k<<<N_GRAPHS, 128, 0, stream>>>(g, W3f, b3f, W4f, b4f, (float*)d_out);
}

// Round 4
// 236.030 us; speedup vs baseline: 1.1909x; 1.1909x over previous
//
#include <hip/hip_runtime.h>
#include <hip/hip_bf16.h>

#define N_NODES  10000
#define N_EDGES  320000
#define N_GRAPHS 64

__device__ __forceinline__ float sigm(float z) { return 1.0f / (1.0f + __expf(-z)); }

// round-to-nearest-even f32 -> bf16 bits
__device__ __forceinline__ unsigned short f2bf(float f) {
    unsigned int u = __float_as_uint(f);
    return (unsigned short)((u + 0x7fffu + ((u >> 16) & 1u)) >> 16);
}
__device__ __forceinline__ float bflo(unsigned int u) { return __uint_as_float(u << 16); }
__device__ __forceinline__ float bfhi(unsigned int u) { return __uint_as_float(u & 0xffff0000u); }

// ---------------- int-width detection ----------------
// flags[0]: edge_index is int32 (1) vs int64 (0); flags[1]: same for batch
__global__ void detect_k(const unsigned int* __restrict__ ei_raw,
                         const unsigned int* __restrict__ batch_raw,
                         int* __restrict__ flags) {
    __shared__ int s[2];
    if (threadIdx.x < 2) s[threadIdx.x] = 0;
    __syncthreads();
    int t = threadIdx.x;
    int nz = 0;
    for (int i = 2 * t + 1; i < 2000; i += 512) nz += (ei_raw[i] != 0);
    if (nz) atomicAdd(&s[0], nz);
    nz = 0;
    for (int i = 2 * t + 1; i < 2000; i += 512) nz += (batch_raw[i] != 0);
    if (nz) atomicAdd(&s[1], nz);
    __syncthreads();
    if (threadIdx.x == 0) {
        flags[0] = s[0] > 10 ? 1 : 0;
        flags[1] = s[1] > 10 ? 1 : 0;
    }
}

// normalize ints to int32 + degree histogram (fused)
__global__ void repack_hist_k(const int* __restrict__ ei, const int* __restrict__ batch,
                              const int* __restrict__ flags, int* __restrict__ src,
                              int* __restrict__ dst, int* __restrict__ bat,
                              int* __restrict__ deg) {
    int i = blockIdx.x * blockDim.x + threadIdx.x;
    int i32e = flags[0], i32b = flags[1];
    if (i < N_EDGES) {
        int s = i32e ? ei[i] : ei[2 * i];
        int d = i32e ? ei[N_EDGES + i] : ei[2 * (N_EDGES + i)];
        src[i] = s;
        dst[i] = d;
        atomicAdd(&deg[d], 1);
    }
    if (i < N_NODES) bat[i] = i32b ? batch[i] : batch[2 * i];
}

// single-pass exclusive scan: 1024 threads x 10 elements
__global__ void scan_k(const int* __restrict__ deg, int* __restrict__ offs,
                       int* __restrict__ cursor, int n) {
    __shared__ int sums[1024];
    int t = threadIdx.x;
    int base = t * 10;
    int v[10];
    int run = 0;
    for (int k = 0; k < 10; k++) {
        int i = base + k;
        int d = (i < n) ? deg[i] : 0;
        v[k] = run;
        run += d;
    }
    sums[t] = run;
    __syncthreads();
    for (int dd = 1; dd < 1024; dd <<= 1) {
        int val = (t >= dd) ? sums[t - dd] : 0;
        __syncthreads();
        sums[t] += val;
        __syncthreads();
    }
    int excl = (t == 0) ? 0 : sums[t - 1];
    for (int k = 0; k < 10; k++) {
        int i = base + k;
        if (i < n) { int o = excl + v[k]; offs[i] = o; cursor[i] = o; }
    }
    if (t == 1023) offs[n] = sums[1023];
}

__global__ void scatter_k(const int* __restrict__ src, const int* __restrict__ dst,
                          int* __restrict__ cursor, int* __restrict__ csr, int E) {
    int e = blockIdx.x * blockDim.x + threadIdx.x;
    if (e < E) {
        int pos = atomicAdd(&cursor[dst[e]], 1);
        csr[pos] = src[e];
    }
}

// ---------------- EdgeConv1 node-level linear parts ----------------
// P1[n][c] = x[n]·(W1[0:3]-W1[3:6])[c] + b1[c]  (f32)
// Q1[n][c] = x[n]·W1[3:6][c]                    (bf16)
__global__ void pq1_k(const float* __restrict__ x, const float* __restrict__ W1,
                      const float* __restrict__ b1, float* __restrict__ P1,
                      unsigned short* __restrict__ Q1, int n) {
    __shared__ float xs[96];
    int c = threadIdx.x;  // 0..255
    float k0, k1, k2, bias;
    if (c < 128) {
        k0 = W1[0 * 128 + c] - W1[3 * 128 + c];
        k1 = W1[1 * 128 + c] - W1[4 * 128 + c];
        k2 = W1[2 * 128 + c] - W1[5 * 128 + c];
        bias = b1[c];
    } else {
        int cc = c - 128;
        k0 = W1[3 * 128 + cc];
        k1 = W1[4 * 128 + cc];
        k2 = W1[5 * 128 + cc];
        bias = 0.f;
    }
    int n0 = blockIdx.x * 32;
    int nmax = min(32, n - n0);
    if (threadIdx.x < 96)
        xs[threadIdx.x] = (threadIdx.x < nmax * 3) ? x[n0 * 3 + threadIdx.x] : 0.f;
    __syncthreads();
    for (int t = 0; t < nmax; t++) {
        float v = bias + xs[t * 3 + 0] * k0 + xs[t * 3 + 1] * k1 + xs[t * 3 + 2] * k2;
        if (c < 128) P1[(n0 + t) * 128 + c] = v;
        else         Q1[(n0 + t) * 128 + (c - 128)] = f2bf(v);
    }
}

// one block (64 thr) per node: h1[i][c] = deg>0 ? sigmoid(P1[i][c] + max_e Q1[src_e][c]) : 0
// each thread handles channels {2c, 2c+1} via packed-uint bf16 loads
__global__ void econv1_k(const float* __restrict__ P1, const unsigned int* __restrict__ Q1u,
                         const int* __restrict__ offs, const int* __restrict__ csr,
                         float* __restrict__ h1) {
    int i = blockIdx.x;
    int c = threadIdx.x;  // 0..63 -> channels 2c, 2c+1
    int s = offs[i], e = offs[i + 1];
    float2 out = make_float2(0.f, 0.f);
    if (e > s) {
        float z0 = -3.4e38f, z1 = -3.4e38f;
        int k = s;
        for (; k + 3 < e; k += 4) {
            int j0 = csr[k], j1 = csr[k + 1], j2 = csr[k + 2], j3 = csr[k + 3];
            unsigned int u0 = Q1u[j0 * 64 + c];
            unsigned int u1 = Q1u[j1 * 64 + c];
            unsigned int u2 = Q1u[j2 * 64 + c];
            unsigned int u3 = Q1u[j3 * 64 + c];
            z0 = fmaxf(z0, fmaxf(fmaxf(bflo(u0), bflo(u1)), fmaxf(bflo(u2), bflo(u3))));
            z1 = fmaxf(z1, fmaxf(fmaxf(bfhi(u0), bfhi(u1)), fmaxf(bfhi(u2), bfhi(u3))));
        }
        for (; k < e; k++) {
            unsigned int u = Q1u[csr[k] * 64 + c];
            z0 = fmaxf(z0, bflo(u));
            z1 = fmaxf(z1, bfhi(u));
        }
        float2 p = *(const float2*)&P1[i * 128 + 2 * c];
        out.x = sigm(p.x + z0);
        out.y = sigm(p.y + z1);
    }
    *(float2*)&h1[i * 128 + 2 * c] = out;
}

// ---------------- EdgeConv2 weights: Wc[128][512] = [A2-B2 | B2] ----------------
__global__ void w2cat_k(const float* __restrict__ W2, float* __restrict__ Wc) {
    int idx = blockIdx.x * blockDim.x + threadIdx.x;
    if (idx < 128 * 512) {
        int k = idx >> 9, j = idx & 511;
        float v;
        if (j < 256) v = W2[k * 256 + j] - W2[(128 + k) * 256 + j];
        else         v = W2[(128 + k) * 256 + (j - 256)];
        Wc[idx] = v;
    }
}

// ---------------- GEMM2: [10000,128] @ [128,512] -> P2 f32 (cols<256, +b2) | Q2 bf16 ----
__global__ __launch_bounds__(256) void gemm2_k(const float* __restrict__ h1,
                                               const float* __restrict__ Wc,
                                               const float* __restrict__ b2,
                                               float* __restrict__ P2,
                                               unsigned short* __restrict__ Q2, int n) {
    __shared__ float As[32][132];
    __shared__ float Bs[128][64];
    int m0 = blockIdx.x * 32;
    int n0 = blockIdx.y * 64;
    int t = threadIdx.x;

    for (int it = 0; it < 4; it++) {
        int f4 = t + it * 256;
        int row = f4 >> 5, col = (f4 & 31) << 2;
        float4 v = make_float4(0.f, 0.f, 0.f, 0.f);
        if (m0 + row < n) v = *(const float4*)&h1[(m0 + row) * 128 + col];
        *(float4*)&As[row][col] = v;
    }
    for (int it = 0; it < 8; it++) {
        int f4 = t + it * 256;
        int row = f4 >> 4, col = (f4 & 15) << 2;
        *(float4*)&Bs[row][col] = *(const float4*)&Wc[row * 512 + n0 + col];
    }
    __syncthreads();

    int tr = t >> 4, tc = t & 15;
    float acc[2][4] = {};
#pragma unroll 4
    for (int k = 0; k < 128; k++) {
        float a0 = As[tr * 2 + 0][k];
        float a1 = As[tr * 2 + 1][k];
        float4 bb = *(float4*)&Bs[k][tc * 4];
        acc[0][0] += a0 * bb.x; acc[0][1] += a0 * bb.y; acc[0][2] += a0 * bb.z; acc[0][3] += a0 * bb.w;
        acc[1][0] += a1 * bb.x; acc[1][1] += a1 * bb.y; acc[1][2] += a1 * bb.z; acc[1][3] += a1 * bb.w;
    }

    int ncol = n0 + tc * 4;
    if (ncol < 256) {
        float bx = b2[ncol + 0], by = b2[ncol + 1], bz = b2[ncol + 2], bw = b2[ncol + 3];
        for (int r = 0; r < 2; r++) {
            int m = m0 + tr * 2 + r;
            if (m < n) {
                float4 o = make_float4(acc[r][0] + bx, acc[r][1] + by, acc[r][2] + bz, acc[r][3] + bw);
                *(float4*)&P2[(size_t)m * 256 + ncol] = o;
            }
        }
    } else {
        int qcol = ncol - 256;
        for (int r = 0; r < 2; r++) {
            int m = m0 + tr * 2 + r;
            if (m < n) {
                ushort4 q;
                q.x = f2bf(acc[r][0]); q.y = f2bf(acc[r][1]);
                q.z = f2bf(acc[r][2]); q.w = f2bf(acc[r][3]);
                *(ushort4*)&Q2[(size_t)m * 256 + qcol] = q;
            }
        }
    }
}

// ---------------- EdgeConv2 + fused graph max-pool ----------------
// one block (128 thr) per node, channels {2c,2c+1} per thread
__global__ void econv2_k(const float* __restrict__ P2, const unsigned int* __restrict__ Q2u,
                         const int* __restrict__ offs, const int* __restrict__ csr,
                         const int* __restrict__ bat, float* __restrict__ g) {
    int i = blockIdx.x;
    int s = offs[i], e = offs[i + 1];
    if (s == e) return;  // empty row -> h2 = 0, contributes nothing (g init 0)
    int c = threadIdx.x;  // 0..127
    float z0 = -3.4e38f, z1 = -3.4e38f;
    int k = s;
    for (; k + 3 < e; k += 4) {
        int j0 = csr[k], j1 = csr[k + 1], j2 = csr[k + 2], j3 = csr[k + 3];
        unsigned int u0 = Q2u[(size_t)j0 * 128 + c];
        unsigned int u1 = Q2u[(size_t)j1 * 128 + c];
        unsigned int u2 = Q2u[(size_t)j2 * 128 + c];
        unsigned int u3 = Q2u[(size_t)j3 * 128 + c];
        z0 = fmaxf(z0, fmaxf(fmaxf(bflo(u0), bflo(u1)), fmaxf(bflo(u2), bflo(u3))));
        z1 = fmaxf(z1, fmaxf(fmaxf(bfhi(u0), bfhi(u1)), fmaxf(bfhi(u2), bfhi(u3))));
    }
    for (; k < e; k++) {
        unsigned int u = Q2u[(size_t)csr[k] * 128 + c];
        z0 = fmaxf(z0, bflo(u));
        z1 = fmaxf(z1, bfhi(u));
    }
    float2 p = *(const float2*)&P2[(size_t)i * 256 + 2 * c];
    float h0 = sigm(p.x + z0);  // > 0 always
    float h1 = sigm(p.y + z1);
    int gb = bat[i] * 256 + 2 * c;
    atomicMax((unsigned int*)&g[gb + 0], __float_as_uint(h0));
    atomicMax((unsigned int*)&g[gb + 1], __float_as_uint(h1));
}

// ---------------- head: out = sigmoid(g@W3+b3)@W4+b4, f32 out ----------------
__global__ void final_k(const float* __restrict__ g, const float* __restrict__ W3,
                        const float* __restrict__ b3, const float* __restrict__ W4,
                        const float* __restrict__ b4, float* __restrict__ out) {
    __shared__ float gs[256];
    __shared__ float ss[128];
    int b = blockIdx.x, t = threadIdx.x;  // 128 threads
    gs[t] = g[b * 256 + t];
    gs[t + 128] = g[b * 256 + 128 + t];
    __syncthreads();
    float acc = b3[t];
#pragma unroll 8
    for (int k = 0; k < 256; k++) acc += gs[k] * W3[k * 128 + t];
    ss[t] = sigm(acc);
    __syncthreads();
    if (t < 10) {
        float o = b4[t];
#pragma unroll 8
        for (int k = 0; k < 128; k++) o += ss[k] * W4[k * 10 + t];
        out[b * 10 + t] = o;
    }
}

extern "C" void kernel_launch(void* const* d_in, const int* in_sizes, int n_in,
                              void* d_out, int out_size, void* d_ws, size_t ws_size,
                              hipStream_t stream) {
    const float* x  = (const float*)d_in[0];
    const void*  ei_raw = d_in[1];
    const void*  b_raw  = d_in[2];
    const float* W1 = (const float*)d_in[3];
    const float* b1 = (const float*)d_in[4];
    const float* W2 = (const float*)d_in[5];
    const float* b2 = (const float*)d_in[6];
    const float* W3 = (const float*)d_in[7];
    const float* b3 = (const float*)d_in[8];
    const float* W4 = (const float*)d_in[9];
    const float* b4 = (const float*)d_in[10];

    char* ws = (char*)d_ws;
    size_t off = 0;
    auto alloc = [&](size_t bytes) {
        void* p = ws + off;
        off += (bytes + 255) & ~(size_t)255;
        return p;
    };
    int*            flags  = (int*)alloc(16);
    int*            src    = (int*)alloc(N_EDGES * 4);
    int*            dst    = (int*)alloc(N_EDGES * 4);
    int*            bat    = (int*)alloc(N_NODES * 4);
    int*            deg    = (int*)alloc(N_NODES * 4);
    int*            offs   = (int*)alloc((N_NODES + 1) * 4);
    int*            cursor = (int*)alloc(N_NODES * 4);
    int*            csr    = (int*)alloc(N_EDGES * 4);
    float*          P1     = (float*)alloc((size_t)N_NODES * 128 * 4);
    unsigned short* Q1     = (unsigned short*)alloc((size_t)N_NODES * 128 * 2);
    float*          h1     = (float*)alloc((size_t)N_NODES * 128 * 4);
    float*          Wc     = (float*)alloc(128 * 512 * 4);
    float*          P2     = (float*)alloc((size_t)N_NODES * 256 * 4);
    unsigned short* Q2     = (unsigned short*)alloc((size_t)N_NODES * 256 * 2);
    float*          g      = (float*)alloc(N_GRAPHS * 256 * 4);

    hipMemsetAsync(deg, 0, N_NODES * 4, stream);
    hipMemsetAsync(g, 0, N_GRAPHS * 256 * 4, stream);

    detect_k<<<1, 256, 0, stream>>>((const unsigned int*)ei_raw, (const unsigned int*)b_raw, flags);
    repack_hist_k<<<(N_EDGES + 255) / 256, 256, 0, stream>>>((const int*)ei_raw, (const int*)b_raw,
                                                             flags, src, dst, bat, deg);
    scan_k<<<1, 1024, 0, stream>>>(deg, offs, cursor, N_NODES);
    scatter_k<<<(N_EDGES + 255) / 256, 256, 0, stream>>>(src, dst, cursor, csr, N_EDGES);

    pq1_k<<<(N_NODES + 31) / 32, 256, 0, stream>>>(x, W1, b1, P1, Q1, N_NODES);
    econv1_k<<<N_NODES, 64, 0, stream>>>(P1, (const unsigned int*)Q1, offs, csr, h1);

    w2cat_k<<<(128 * 512) / 256, 256, 0, stream>>>(W2, Wc);
    gemm2_k<<<dim3((N_NODES + 31) / 32, 8), 256, 0, stream>>>(h1, Wc, b2, P2, Q2, N_NODES);

    econv2_k<<<N_NODES, 128, 0, stream>>>(P2, (const unsigned int*)Q2, offs, csr, bat, g);
    final_k<<<N_GRAPHS, 128, 0, stream>>>(g, W3, b3, W4, b4, (float*)d_out);
}